// Round 14
// baseline (365.835 us; speedup 1.0000x reference)
//
#include <hip/hip_runtime.h>
#include <stdint.h>

typedef float v4f __attribute__((ext_vector_type(4)));
typedef __bf16 v8bf __attribute__((ext_vector_type(8)));
typedef __bf16 v4bf __attribute__((ext_vector_type(4)));
typedef unsigned short v8us __attribute__((ext_vector_type(8)));
typedef unsigned short v4us __attribute__((ext_vector_type(4)));

__device__ __forceinline__ float b2f(unsigned short u) {
    union { float f; uint32_t i; } x; x.i = ((uint32_t)u) << 16; return x.f;
}
__device__ __forceinline__ unsigned short f2b(float f) {
    union { float f; uint32_t u; } x; x.f = f;
    uint32_t r = x.u + 0x7fffu + ((x.u >> 16) & 1u);
    return (unsigned short)(r >> 16);
}

// ---------------------------------------------------------------------------
// fp32 -> bf16 convert (x), 4 elems/thread.
// ---------------------------------------------------------------------------
__global__ __launch_bounds__(256) void convert_f32_bf16(
    const float* __restrict__ src, unsigned short* __restrict__ dst)
{
    int i = (blockIdx.x * 256 + threadIdx.x) * 4;
    float4 v = *(const float4*)&src[i];
    v4us o = {f2b(v.x), f2b(v.y), f2b(v.z), f2b(v.w)};
    *(v4us*)&dst[i] = o;
}

// ---------------------------------------------------------------------------
// W[K][N] fp32 -> WT[N][K] bf16, 64x64 LDS tile, block 256.
// ---------------------------------------------------------------------------
__global__ __launch_bounds__(256) void transpose_to_bt(
    const float* __restrict__ W, unsigned short* __restrict__ WT, int K, int N)
{
    __shared__ unsigned short t[64][65];
    const int kb = blockIdx.y * 64, nb = blockIdx.x * 64;
    const int r = threadIdx.x >> 4, c4 = (threadIdx.x & 15) * 4;
    #pragma unroll
    for (int i = 0; i < 4; ++i) {
        int k = r + i * 16;
        float4 v = *(const float4*)&W[(size_t)(kb + k) * N + nb + c4];
        t[c4 + 0][k] = f2b(v.x);
        t[c4 + 1][k] = f2b(v.y);
        t[c4 + 2][k] = f2b(v.z);
        t[c4 + 3][k] = f2b(v.w);
    }
    __syncthreads();
    #pragma unroll
    for (int i = 0; i < 4; ++i) {
        int n = r + i * 16;
        v4us o = {t[n][c4], t[n][c4 + 1], t[n][c4 + 2], t[n][c4 + 3]};
        *(v4us*)&WT[(size_t)(nb + n) * K + kb + c4] = o;
    }
}

// ---------------------------------------------------------------------------
// GEMM, BK=64 dual-chunk, register-prefetch staging (r12, known good).
// C = A @ BT^T + bias, opt ReLU. 128x128 tile.
// SPLIT_V (QKV GEMM): V tiles -> VT[bh][d][seq] transposed; Q tiles are
// PRE-SCALED by 0.125*log2e so attention's exp2 needs no per-score multiply.
// ---------------------------------------------------------------------------
template<int SPLIT_V>
__global__ __launch_bounds__(256) void gemm_bt(
    const unsigned short* __restrict__ A, const unsigned short* __restrict__ BT,
    const float* __restrict__ bias, unsigned short* __restrict__ C,
    unsigned short* __restrict__ VT, int M, int N, int K, int relu)
{
    __shared__ __align__(16) unsigned short sA[2][128 * 32];
    __shared__ __align__(16) unsigned short sB[2][128 * 32];
    const int tid  = threadIdx.x;
    const int wave = tid >> 6, lane = tid & 63;
    const int wm = wave >> 1, wn = wave & 1;
    const int quad = lane >> 4, l16 = lane & 15;
    const int bm = blockIdx.y, bn = blockIdx.x;

    const int srow = lane >> 2, scol = (lane & 3) * 8;
    const unsigned short* ga0 = A  + (size_t)(bm * 128 + (wave * 2 + 0) * 16 + srow) * K + scol;
    const unsigned short* ga1 = A  + (size_t)(bm * 128 + (wave * 2 + 1) * 16 + srow) * K + scol;
    const unsigned short* gb0 = BT + (size_t)(bn * 128 + (wave * 2 + 0) * 16 + srow) * K + scol;
    const unsigned short* gb1 = BT + (size_t)(bn * 128 + (wave * 2 + 1) * 16 + srow) * K + scol;
    const int o0 = (wave * 2 + 0) * 512 + lane * 8;
    const int o1 = (wave * 2 + 1) * 512 + lane * 8;

    v8us aR[2][2], bR[2][2];
    #pragma unroll
    for (int c = 0; c < 2; ++c) {
        aR[c][0] = *(const v8us*)(ga0 + c * 32);
        aR[c][1] = *(const v8us*)(ga1 + c * 32);
        bR[c][0] = *(const v8us*)(gb0 + c * 32);
        bR[c][1] = *(const v8us*)(gb1 + c * 32);
    }

    v4f acc[4][4];
    #pragma unroll
    for (int i = 0; i < 4; ++i)
        #pragma unroll
        for (int j = 0; j < 4; ++j)
            acc[i][j] = (v4f){0.f, 0.f, 0.f, 0.f};

    for (int kt = 0; kt < K; kt += 64) {
        __syncthreads();
        #pragma unroll
        for (int c = 0; c < 2; ++c) {
            *(v8us*)&sA[c][o0] = aR[c][0];
            *(v8us*)&sA[c][o1] = aR[c][1];
            *(v8us*)&sB[c][o0] = bR[c][0];
            *(v8us*)&sB[c][o1] = bR[c][1];
        }
        __syncthreads();
        if (kt + 64 < K) {
            int kn = kt + 64;
            #pragma unroll
            for (int c = 0; c < 2; ++c) {
                aR[c][0] = *(const v8us*)(ga0 + kn + c * 32);
                aR[c][1] = *(const v8us*)(ga1 + kn + c * 32);
                bR[c][0] = *(const v8us*)(gb0 + kn + c * 32);
                bR[c][1] = *(const v8us*)(gb1 + kn + c * 32);
            }
        }

        #pragma unroll
        for (int c = 0; c < 2; ++c) {
            v8bf af[4], bfr[4];
            #pragma unroll
            for (int mt = 0; mt < 4; ++mt)
                af[mt] = *(const v8bf*)&sA[c][(wm * 64 + mt * 16 + l16) * 32 + quad * 8];
            #pragma unroll
            for (int nt = 0; nt < 4; ++nt)
                bfr[nt] = *(const v8bf*)&sB[c][(wn * 64 + nt * 16 + l16) * 32 + quad * 8];
            #pragma unroll
            for (int mt = 0; mt < 4; ++mt)
                #pragma unroll
                for (int nt = 0; nt < 4; ++nt)
                    acc[mt][nt] = __builtin_amdgcn_mfma_f32_16x16x32_bf16(
                        af[mt], bfr[nt], acc[mt][nt], 0, 0, 0);
        }
    }

    #pragma unroll
    for (int mt = 0; mt < 4; ++mt) {
        int row = bm * 128 + wm * 64 + mt * 16 + quad * 4;
        #pragma unroll
        for (int nt = 0; nt < 4; ++nt) {
            int c0 = bn * 128 + wn * 64 + nt * 16;
            int col = c0 + l16;
            float bv = bias ? bias[col] : 0.f;
            if (SPLIT_V && (c0 % 192) >= 128) {
                int hh = c0 / 192;
                int d  = (c0 % 192) - 128 + l16;
                int bb = row >> 11;
                int s  = row & 2047;
                v4us st;
                #pragma unroll
                for (int r = 0; r < 4; ++r)
                    st[r] = f2b(acc[mt][nt][r] + bv);
                *(v4us*)&VT[((size_t)(bb * 16 + hh) * 64 + d) * 2048 + s] = st;
            } else {
                // Q tiles (col%192 < 64) pre-scaled by 0.125*log2e
                float qs = (SPLIT_V && (c0 % 192) < 64) ? 0.18033688f : 1.0f;
                #pragma unroll
                for (int r = 0; r < 4; ++r) {
                    float v = (acc[mt][nt][r] + bv) * qs;
                    if (relu) v = fmaxf(v, 0.f);
                    C[(size_t)(row + r) * N + col] = f2b(v);
                }
            }
        }
    }
}

// ---------------------------------------------------------------------------
// 128x64-tile GEMM for narrow-N (N=1024), BK=64, register-prefetch (r12).
// ---------------------------------------------------------------------------
__global__ __launch_bounds__(256) void gemm_bt_n64(
    const unsigned short* __restrict__ A, const unsigned short* __restrict__ BT,
    const float* __restrict__ bias, unsigned short* __restrict__ C,
    int M, int N, int K, int relu)
{
    __shared__ __align__(16) unsigned short sA[2][128 * 32];
    __shared__ __align__(16) unsigned short sB[2][64 * 32];
    const int tid  = threadIdx.x;
    const int wave = tid >> 6, lane = tid & 63;
    const int wm = wave >> 1, wn = wave & 1;
    const int quad = lane >> 4, l16 = lane & 15;
    const int bm = blockIdx.y, bn = blockIdx.x;

    const int srow = lane >> 2, scol = (lane & 3) * 8;
    const unsigned short* ga0 = A  + (size_t)(bm * 128 + (wave * 2 + 0) * 16 + srow) * K + scol;
    const unsigned short* ga1 = A  + (size_t)(bm * 128 + (wave * 2 + 1) * 16 + srow) * K + scol;
    const unsigned short* gb0 = BT + (size_t)(bn * 64 + wave * 16 + srow) * K + scol;
    const int oa0 = (wave * 2 + 0) * 512 + lane * 8;
    const int oa1 = (wave * 2 + 1) * 512 + lane * 8;
    const int ob  = wave * 512 + lane * 8;

    v8us aR[2][2], bR[2];
    #pragma unroll
    for (int c = 0; c < 2; ++c) {
        aR[c][0] = *(const v8us*)(ga0 + c * 32);
        aR[c][1] = *(const v8us*)(ga1 + c * 32);
        bR[c]    = *(const v8us*)(gb0 + c * 32);
    }

    v4f acc[4][2];
    #pragma unroll
    for (int i = 0; i < 4; ++i)
        #pragma unroll
        for (int j = 0; j < 2; ++j)
            acc[i][j] = (v4f){0.f, 0.f, 0.f, 0.f};

    for (int kt = 0; kt < K; kt += 64) {
        __syncthreads();
        #pragma unroll
        for (int c = 0; c < 2; ++c) {
            *(v8us*)&sA[c][oa0] = aR[c][0];
            *(v8us*)&sA[c][oa1] = aR[c][1];
            *(v8us*)&sB[c][ob]  = bR[c];
        }
        __syncthreads();
        if (kt + 64 < K) {
            int kn = kt + 64;
            #pragma unroll
            for (int c = 0; c < 2; ++c) {
                aR[c][0] = *(const v8us*)(ga0 + kn + c * 32);
                aR[c][1] = *(const v8us*)(ga1 + kn + c * 32);
                bR[c]    = *(const v8us*)(gb0 + kn + c * 32);
            }
        }

        #pragma unroll
        for (int c = 0; c < 2; ++c) {
            v8bf af[4], bfr[2];
            #pragma unroll
            for (int mt = 0; mt < 4; ++mt)
                af[mt] = *(const v8bf*)&sA[c][(wm * 64 + mt * 16 + l16) * 32 + quad * 8];
            #pragma unroll
            for (int nt = 0; nt < 2; ++nt)
                bfr[nt] = *(const v8bf*)&sB[c][(wn * 32 + nt * 16 + l16) * 32 + quad * 8];
            #pragma unroll
            for (int mt = 0; mt < 4; ++mt)
                #pragma unroll
                for (int nt = 0; nt < 2; ++nt)
                    acc[mt][nt] = __builtin_amdgcn_mfma_f32_16x16x32_bf16(
                        af[mt], bfr[nt], acc[mt][nt], 0, 0, 0);
        }
    }

    #pragma unroll
    for (int mt = 0; mt < 4; ++mt) {
        #pragma unroll
        for (int nt = 0; nt < 2; ++nt) {
            int col = bn * 64 + wn * 32 + nt * 16 + l16;
            float bv = bias ? bias[col] : 0.f;
            #pragma unroll
            for (int r = 0; r < 4; ++r) {
                int row = bm * 128 + wm * 64 + mt * 16 + quad * 4 + r;
                float v = acc[mt][nt][r] + bv;
                if (relu) v = fmaxf(v, 0.f);
                C[(size_t)row * N + col] = f2b(v);
            }
        }
    }
}

// ---------------------------------------------------------------------------
// MFMA flash attention v8: 32 q/wave (r13) + XCD-locality swizzle — all 16
// q-blocks of one (b,h) map to the same XCD (assuming round-robin dispatch
// blk%8 -> XCD): per-XCD K/V working set = 4 bh x 512 KB = 2 MB < 4 MB L2,
// so the 16x K/V re-reads hit local L2 instead of cross-die L3.
// Q comes PRE-SCALED by 0.125*log2e -> p = exp2(sc) directly.
// ---------------------------------------------------------------------------
__global__ __launch_bounds__(256) void attn_mfma(
    const unsigned short* __restrict__ qkv, const unsigned short* __restrict__ VT,
    unsigned short* __restrict__ av)
{
    __shared__ __align__(16) unsigned short sK[64 * 72];      // [key][d]
    __shared__ __align__(16) unsigned short sVT[64 * 72];     // [d][key]
    __shared__ __align__(16) unsigned short sP[4][32 * 72];   // per wave [q][key]
    const int tid  = threadIdx.x;
    const int wave = tid >> 6, lane = tid & 63;
    const int quad = lane >> 4, l16 = lane & 15;
    const int blk = blockIdx.x;              // 512 blocks
    // XCD swizzle: xcd = blk&7, 64 blocks per XCD = 4 bh x 16 qb
    const int xcd = blk & 7, local = blk >> 3;
    const int bh = xcd * 4 + (local & 3);
    const int qb = local >> 2;
    const int h = bh & 15, b = bh >> 4;
    const int row0 = b * 2048;
    const int qbase = row0 + qb * 128 + wave * 32;
    const size_t qoff = (size_t)h * 192;
    const size_t koff = qoff + 64;

    v8bf qf[2][2];
    #pragma unroll
    for (int qt = 0; qt < 2; ++qt)
        #pragma unroll
        for (int kc = 0; kc < 2; ++kc)
            qf[qt][kc] = *(const v8bf*)&qkv[(size_t)(qbase + qt * 16 + l16) * 3072
                                            + qoff + kc * 32 + quad * 8];

    v4f o[4][2];
    #pragma unroll
    for (int dt = 0; dt < 4; ++dt)
        #pragma unroll
        for (int qt = 0; qt < 2; ++qt)
            o[dt][qt] = (v4f){0.f, 0.f, 0.f, 0.f};
    float ll[2] = {0.f, 0.f};

    const int k_key0 = tid >> 3,        k_oct = (tid & 7) * 8;
    const int k_key1 = (tid + 256) >> 3;
    const int v_d0 = tid >> 3,          v_koct = (tid & 7) * 8;
    const int v_d1 = (tid + 256) >> 3;
    const unsigned short* gK0 = qkv + (size_t)(row0 + k_key0) * 3072 + koff + k_oct;
    const unsigned short* gK1 = qkv + (size_t)(row0 + k_key1) * 3072 + koff + k_oct;
    const unsigned short* gV0 = VT + ((size_t)bh * 64 + v_d0) * 2048 + v_koct;
    const unsigned short* gV1 = VT + ((size_t)bh * 64 + v_d1) * 2048 + v_koct;
    const size_t stepK = (size_t)64 * 3072;
    const size_t stepV = 64;

    v8us kreg0 = *(const v8us*)gK0, kreg1 = *(const v8us*)gK1;
    v8us vreg0 = *(const v8us*)gV0, vreg1 = *(const v8us*)gV1;
    gK0 += stepK; gK1 += stepK; gV0 += stepV; gV1 += stepV;

    for (int kt = 0; kt < 32; ++kt) {
        __syncthreads();
        *(v8us*)&sK[k_key0 * 72 + k_oct] = kreg0;
        *(v8us*)&sK[k_key1 * 72 + k_oct] = kreg1;
        *(v8us*)&sVT[v_d0 * 72 + v_koct] = vreg0;
        *(v8us*)&sVT[v_d1 * 72 + v_koct] = vreg1;
        __syncthreads();
        if (kt < 31) {               // prefetch next tile (overlaps compute)
            kreg0 = *(const v8us*)gK0; kreg1 = *(const v8us*)gK1;
            vreg0 = *(const v8us*)gV0; vreg1 = *(const v8us*)gV1;
            gK0 += stepK; gK1 += stepK; gV0 += stepV; gV1 += stepV;
        }

        // ---- S^T = K . Q^T  (ak reused across both q-tiles) ----
        v4f sc[4][2];
        #pragma unroll
        for (int kk = 0; kk < 4; ++kk) {
            #pragma unroll
            for (int qt = 0; qt < 2; ++qt)
                sc[kk][qt] = (v4f){0.f, 0.f, 0.f, 0.f};
            #pragma unroll
            for (int kc = 0; kc < 2; ++kc) {
                v8bf ak = *(const v8bf*)&sK[(kk * 16 + l16) * 72 + kc * 32 + quad * 8];
                #pragma unroll
                for (int qt = 0; qt < 2; ++qt)
                    sc[kk][qt] = __builtin_amdgcn_mfma_f32_16x16x32_bf16(
                        ak, qf[qt][kc], sc[kk][qt], 0, 0, 0);
            }
        }

        // ---- softmax numerators: Q pre-scaled -> p = 2^sc directly ----
        #pragma unroll
        for (int qt = 0; qt < 2; ++qt) {
            float ps = 0.f;
            #pragma unroll
            for (int kk = 0; kk < 4; ++kk) {
                v4bf pk;
                #pragma unroll
                for (int rr = 0; rr < 4; ++rr) {
                    float p = __builtin_amdgcn_exp2f(sc[kk][qt][rr]);
                    ps += p;
                    pk[rr] = (__bf16)p;
                }
                *(v4bf*)&sP[wave][(qt * 16 + l16) * 72 + kk * 16 + quad * 4] = pk;
            }
            ll[qt] += ps;
        }

        __asm__ volatile("s_waitcnt lgkmcnt(0)" ::: "memory");

        // ---- O^T += V^T . P^T  (va reused across both q-tiles) ----
        #pragma unroll
        for (int c = 0; c < 2; ++c) {
            v8bf pb[2];
            #pragma unroll
            for (int qt = 0; qt < 2; ++qt) {
                union { v8bf v; v8us u; } u;
                u.u = *(const v8us*)&sP[wave][(qt * 16 + l16) * 72 + c * 32 + quad * 8];
                pb[qt] = u.v;
            }
            #pragma unroll
            for (int dt = 0; dt < 4; ++dt) {
                v8bf va = *(const v8bf*)&sVT[(dt * 16 + l16) * 72 + c * 32 + quad * 8];
                #pragma unroll
                for (int qt = 0; qt < 2; ++qt)
                    o[dt][qt] = __builtin_amdgcn_mfma_f32_16x16x32_bf16(
                        va, pb[qt], o[dt][qt], 0, 0, 0);
            }
        }
    }

    // ---- epilogue ----
    #pragma unroll
    for (int qt = 0; qt < 2; ++qt) {
        float l = ll[qt];
        l += __shfl_xor(l, 16, 64);
        l += __shfl_xor(l, 32, 64);
        float inv = 1.f / l;
        int qrow = qbase + qt * 16 + l16;
        #pragma unroll
        for (int dt = 0; dt < 4; ++dt) {
            v4bf st;
            #pragma unroll
            for (int rr = 0; rr < 4; ++rr)
                st[rr] = (__bf16)(o[dt][qt][rr] * inv);
            *(v4bf*)&av[(size_t)qrow * 1024 + h * 64 + dt * 16 + quad * 4] = st;
        }
    }
}

// ---------------------------------------------------------------------------
// Fused residual-add + LayerNorm (unchanged — known good)
// ---------------------------------------------------------------------------
template<int RES_F32, int OUT_F32>
__global__ __launch_bounds__(256) void ln_fused(
    const unsigned short* __restrict__ a, const void* __restrict__ residv,
    const float* __restrict__ gamma, const float* __restrict__ beta,
    void* __restrict__ outv)
{
    const int row = blockIdx.x, tid = threadIdx.x;
    const size_t base = (size_t)row * 1024;
    const int c0 = tid * 4;
    ushort4 avv = *(const ushort4*)&a[base + c0];
    float y[4];
    if (RES_F32) {
        float4 rv = *(const float4*)((const float*)residv + base + c0);
        y[0] = b2f(avv.x) + rv.x;
        y[1] = b2f(avv.y) + rv.y;
        y[2] = b2f(avv.z) + rv.z;
        y[3] = b2f(avv.w) + rv.w;
    } else {
        ushort4 rv = *(const ushort4*)((const unsigned short*)residv + base + c0);
        y[0] = b2f(avv.x) + b2f(rv.x);
        y[1] = b2f(avv.y) + b2f(rv.y);
        y[2] = b2f(avv.z) + b2f(rv.z);
        y[3] = b2f(avv.w) + b2f(rv.w);
    }
    float s  = y[0] + y[1] + y[2] + y[3];
    float ss = y[0]*y[0] + y[1]*y[1] + y[2]*y[2] + y[3]*y[3];
    #pragma unroll
    for (int off = 32; off; off >>= 1) {
        s  += __shfl_xor(s, off, 64);
        ss += __shfl_xor(ss, off, 64);
    }
    __shared__ float red[8];
    int wave = tid >> 6, lane = tid & 63;
    if (lane == 0) { red[wave] = s; red[4 + wave] = ss; }
    __syncthreads();
    s  = red[0] + red[1] + red[2] + red[3];
    ss = red[4] + red[5] + red[6] + red[7];
    float mean = s * (1.f / 1024.f);
    float var  = ss * (1.f / 1024.f) - mean * mean;
    float rstd = rsqrtf(var + 1e-5f);
    float4 gv = *(const float4*)&gamma[c0];
    float4 bv = *(const float4*)&beta[c0];
    float r0 = gv.x * (y[0] - mean) * rstd + bv.x;
    float r1 = gv.y * (y[1] - mean) * rstd + bv.y;
    float r2 = gv.z * (y[2] - mean) * rstd + bv.z;
    float r3 = gv.w * (y[3] - mean) * rstd + bv.w;
    if (OUT_F32) {
        float4 ov = {r0, r1, r2, r3};
        *(float4*)((float*)outv + base + c0) = ov;
    } else {
        ushort4 ov;
        ov.x = f2b(r0); ov.y = f2b(r1); ov.z = f2b(r2); ov.w = f2b(r3);
        *(ushort4*)((unsigned short*)outv + base + c0) = ov;
    }
}

// ---------------------------------------------------------------------------
extern "C" void kernel_launch(void* const* d_in, const int* in_sizes, int n_in,
                              void* d_out, int out_size, void* d_ws, size_t ws_size,
                              hipStream_t stream)
{
    (void)in_sizes; (void)n_in; (void)out_size; (void)ws_size;
    const float* x    = (const float*)d_in[0];
    const float* Wqkv = (const float*)d_in[1];
    const float* bqkv = (const float*)d_in[2];
    const float* Wo   = (const float*)d_in[3];
    const float* bo   = (const float*)d_in[4];
    const float* g1   = (const float*)d_in[5];
    const float* be1  = (const float*)d_in[6];
    const float* W1   = (const float*)d_in[7];
    const float* b1   = (const float*)d_in[8];
    const float* W2   = (const float*)d_in[9];
    const float* b2   = (const float*)d_in[10];
    const float* g2   = (const float*)d_in[11];
    const float* be2  = (const float*)d_in[12];
    float* out = (float*)d_out;

    // ws regions (bf16 elems), 28M total. Lifetimes:
    //  R0 (16M): qkv Q/K -> ffn1; tail [12M..16M]: WqkvT
    //  R1 (4M):  VT -> attn_out -> W2T
    //  R2 (4M):  xb -> WoT -> h
    //  R3 (4M):  av -> W1T -> ffn2
    unsigned short* R0 = (unsigned short*)d_ws;
    unsigned short* R1 = R0 + (size_t)16 * 1024 * 1024;
    unsigned short* R2 = R1 + (size_t)4 * 1024 * 1024;
    unsigned short* R3 = R2 + (size_t)4 * 1024 * 1024;
    unsigned short* WqkvT = R0 + (size_t)12 * 1024 * 1024;

    const int M = 4096;
    dim3 blk(256);

    // prep: x -> bf16 (R2); Wqkv^T (into R0 tail)
    convert_f32_bf16<<<dim3(M * 1024 / 1024), blk, 0, stream>>>(x, R2);
    transpose_to_bt<<<dim3(48, 16), blk, 0, stream>>>(Wqkv, WqkvT, 1024, 3072);
    // 1. qkv = xb @ Wqkv + b -> Q(pre-scaled)/K into R0, V transposed into VT (R1)
    gemm_bt<1><<<dim3(24, 32), blk, 0, stream>>>(R2, WqkvT, bqkv, R0, R1, M, 3072, 1024, 0);
    // 2. attention -> av (R3)
    attn_mfma<<<dim3(512), blk, 0, stream>>>(R0, R1, R3);
    // 3. attn_out = av @ Wo + bo -> R1   (VT dead)
    transpose_to_bt<<<dim3(16, 16), blk, 0, stream>>>(Wo, R2, 1024, 1024);
    gemm_bt_n64<<<dim3(16, 32), blk, 0, stream>>>(R3, R2, bo, R1, M, 1024, 1024, 0);
    // 4. h = LN1(attn_out + x) -> R2  (WoT dead)
    ln_fused<1, 0><<<dim3(4096), blk, 0, stream>>>(R1, x, g1, be1, R2);
    // 5. ffn1 = relu(h @ W1 + b1) -> R0  (qkv dead)
    transpose_to_bt<<<dim3(64, 16), blk, 0, stream>>>(W1, R3, 1024, 4096);
    gemm_bt<0><<<dim3(32, 32), blk, 0, stream>>>(R2, R3, b1, R0, nullptr, M, 4096, 1024, 1);
    // 6. ffn2 = ffn1 @ W2 + b2 -> R3  (W1T dead)
    transpose_to_bt<<<dim3(16, 64), blk, 0, stream>>>(W2, R1, 4096, 1024);
    gemm_bt_n64<<<dim3(16, 32), blk, 0, stream>>>(R0, R1, b2, R3, M, 1024, 4096, 0);
    // 7. out = LN2(ffn2 + h)
    ln_fused<0, 1><<<dim3(4096), blk, 0, stream>>>(R3, R2, g2, be2, out);
}

// Round 15
// 348.177 us; speedup vs baseline: 1.0507x; 1.0507x over previous
//
#include <hip/hip_runtime.h>
#include <stdint.h>

typedef float v4f __attribute__((ext_vector_type(4)));
typedef __bf16 v8bf __attribute__((ext_vector_type(8)));
typedef __bf16 v4bf __attribute__((ext_vector_type(4)));
typedef unsigned short v8us __attribute__((ext_vector_type(8)));
typedef unsigned short v4us __attribute__((ext_vector_type(4)));

__device__ __forceinline__ float b2f(unsigned short u) {
    union { float f; uint32_t i; } x; x.i = ((uint32_t)u) << 16; return x.f;
}
__device__ __forceinline__ unsigned short f2b(float f) {
    union { float f; uint32_t u; } x; x.f = f;
    uint32_t r = x.u + 0x7fffu + ((x.u >> 16) & 1u);
    return (unsigned short)(r >> 16);
}

// ---------------------------------------------------------------------------
// fp32 -> bf16 convert (x), 4 elems/thread.
// ---------------------------------------------------------------------------
__global__ __launch_bounds__(256) void convert_f32_bf16(
    const float* __restrict__ src, unsigned short* __restrict__ dst)
{
    int i = (blockIdx.x * 256 + threadIdx.x) * 4;
    float4 v = *(const float4*)&src[i];
    v4us o = {f2b(v.x), f2b(v.y), f2b(v.z), f2b(v.w)};
    *(v4us*)&dst[i] = o;
}

// ---------------------------------------------------------------------------
// W[K][N] fp32 -> WT[N][K] bf16, 64x64 LDS tile, block 256.
// ---------------------------------------------------------------------------
__global__ __launch_bounds__(256) void transpose_to_bt(
    const float* __restrict__ W, unsigned short* __restrict__ WT, int K, int N)
{
    __shared__ unsigned short t[64][65];
    const int kb = blockIdx.y * 64, nb = blockIdx.x * 64;
    const int r = threadIdx.x >> 4, c4 = (threadIdx.x & 15) * 4;
    #pragma unroll
    for (int i = 0; i < 4; ++i) {
        int k = r + i * 16;
        float4 v = *(const float4*)&W[(size_t)(kb + k) * N + nb + c4];
        t[c4 + 0][k] = f2b(v.x);
        t[c4 + 1][k] = f2b(v.y);
        t[c4 + 2][k] = f2b(v.z);
        t[c4 + 3][k] = f2b(v.w);
    }
    __syncthreads();
    #pragma unroll
    for (int i = 0; i < 4; ++i) {
        int n = r + i * 16;
        v4us o = {t[n][c4], t[n][c4 + 1], t[n][c4 + 2], t[n][c4 + 3]};
        *(v4us*)&WT[(size_t)(nb + n) * K + kb + c4] = o;
    }
}

// ---------------------------------------------------------------------------
// XCD-locality swizzle for GEMM grids: each XCD gets a contiguous m-band
// (MB/8 m-blocks -> A-tiles stay in local L2) x all n-columns, m fastest so
// co-running blocks share B-tiles. Assumes round-robin flat%8 -> XCD
// (validated r14: attention FETCH 69.7 -> 12.3 MB). MB must be %8 (all are 32).
// ---------------------------------------------------------------------------
__device__ __forceinline__ void xcd_swizzle(int& bm, int& bn) {
    int NB = gridDim.x, MB = gridDim.y;
    int flat = blockIdx.x + NB * blockIdx.y;
    int xcd = flat & 7, j = flat >> 3;
    int MBand = MB >> 3;
    bm = xcd * MBand + (j % MBand);
    bn = j / MBand;
}

// ---------------------------------------------------------------------------
// GEMM, BK=64 dual-chunk, register-prefetch staging (r12) + XCD m-band
// swizzle. C = A @ BT^T + bias, opt ReLU. 128x128 tile.
// SPLIT_V (QKV GEMM): V tiles -> VT[bh][d][seq] transposed; Q tiles
// pre-scaled by 0.125*log2e.
// ---------------------------------------------------------------------------
template<int SPLIT_V>
__global__ __launch_bounds__(256) void gemm_bt(
    const unsigned short* __restrict__ A, const unsigned short* __restrict__ BT,
    const float* __restrict__ bias, unsigned short* __restrict__ C,
    unsigned short* __restrict__ VT, int M, int N, int K, int relu)
{
    __shared__ __align__(16) unsigned short sA[2][128 * 32];
    __shared__ __align__(16) unsigned short sB[2][128 * 32];
    const int tid  = threadIdx.x;
    const int wave = tid >> 6, lane = tid & 63;
    const int wm = wave >> 1, wn = wave & 1;
    const int quad = lane >> 4, l16 = lane & 15;
    int bm, bn;
    xcd_swizzle(bm, bn);

    const int srow = lane >> 2, scol = (lane & 3) * 8;
    const unsigned short* ga0 = A  + (size_t)(bm * 128 + (wave * 2 + 0) * 16 + srow) * K + scol;
    const unsigned short* ga1 = A  + (size_t)(bm * 128 + (wave * 2 + 1) * 16 + srow) * K + scol;
    const unsigned short* gb0 = BT + (size_t)(bn * 128 + (wave * 2 + 0) * 16 + srow) * K + scol;
    const unsigned short* gb1 = BT + (size_t)(bn * 128 + (wave * 2 + 1) * 16 + srow) * K + scol;
    const int o0 = (wave * 2 + 0) * 512 + lane * 8;
    const int o1 = (wave * 2 + 1) * 512 + lane * 8;

    v8us aR[2][2], bR[2][2];
    #pragma unroll
    for (int c = 0; c < 2; ++c) {
        aR[c][0] = *(const v8us*)(ga0 + c * 32);
        aR[c][1] = *(const v8us*)(ga1 + c * 32);
        bR[c][0] = *(const v8us*)(gb0 + c * 32);
        bR[c][1] = *(const v8us*)(gb1 + c * 32);
    }

    v4f acc[4][4];
    #pragma unroll
    for (int i = 0; i < 4; ++i)
        #pragma unroll
        for (int j = 0; j < 4; ++j)
            acc[i][j] = (v4f){0.f, 0.f, 0.f, 0.f};

    for (int kt = 0; kt < K; kt += 64) {
        __syncthreads();
        #pragma unroll
        for (int c = 0; c < 2; ++c) {
            *(v8us*)&sA[c][o0] = aR[c][0];
            *(v8us*)&sA[c][o1] = aR[c][1];
            *(v8us*)&sB[c][o0] = bR[c][0];
            *(v8us*)&sB[c][o1] = bR[c][1];
        }
        __syncthreads();
        if (kt + 64 < K) {
            int kn = kt + 64;
            #pragma unroll
            for (int c = 0; c < 2; ++c) {
                aR[c][0] = *(const v8us*)(ga0 + kn + c * 32);
                aR[c][1] = *(const v8us*)(ga1 + kn + c * 32);
                bR[c][0] = *(const v8us*)(gb0 + kn + c * 32);
                bR[c][1] = *(const v8us*)(gb1 + kn + c * 32);
            }
        }

        #pragma unroll
        for (int c = 0; c < 2; ++c) {
            v8bf af[4], bfr[4];
            #pragma unroll
            for (int mt = 0; mt < 4; ++mt)
                af[mt] = *(const v8bf*)&sA[c][(wm * 64 + mt * 16 + l16) * 32 + quad * 8];
            #pragma unroll
            for (int nt = 0; nt < 4; ++nt)
                bfr[nt] = *(const v8bf*)&sB[c][(wn * 64 + nt * 16 + l16) * 32 + quad * 8];
            #pragma unroll
            for (int mt = 0; mt < 4; ++mt)
                #pragma unroll
                for (int nt = 0; nt < 4; ++nt)
                    acc[mt][nt] = __builtin_amdgcn_mfma_f32_16x16x32_bf16(
                        af[mt], bfr[nt], acc[mt][nt], 0, 0, 0);
        }
    }

    #pragma unroll
    for (int mt = 0; mt < 4; ++mt) {
        int row = bm * 128 + wm * 64 + mt * 16 + quad * 4;
        #pragma unroll
        for (int nt = 0; nt < 4; ++nt) {
            int c0 = bn * 128 + wn * 64 + nt * 16;
            int col = c0 + l16;
            float bv = bias ? bias[col] : 0.f;
            if (SPLIT_V && (c0 % 192) >= 128) {
                int hh = c0 / 192;
                int d  = (c0 % 192) - 128 + l16;
                int bb = row >> 11;
                int s  = row & 2047;
                v4us st;
                #pragma unroll
                for (int r = 0; r < 4; ++r)
                    st[r] = f2b(acc[mt][nt][r] + bv);
                *(v4us*)&VT[((size_t)(bb * 16 + hh) * 64 + d) * 2048 + s] = st;
            } else {
                float qs = (SPLIT_V && (c0 % 192) < 64) ? 0.18033688f : 1.0f;
                #pragma unroll
                for (int r = 0; r < 4; ++r) {
                    float v = (acc[mt][nt][r] + bv) * qs;
                    if (relu) v = fmaxf(v, 0.f);
                    C[(size_t)(row + r) * N + col] = f2b(v);
                }
            }
        }
    }
}

// ---------------------------------------------------------------------------
// 128x64-tile GEMM for narrow-N (N=1024), BK=64, register-prefetch + XCD
// m-band swizzle.
// ---------------------------------------------------------------------------
__global__ __launch_bounds__(256) void gemm_bt_n64(
    const unsigned short* __restrict__ A, const unsigned short* __restrict__ BT,
    const float* __restrict__ bias, unsigned short* __restrict__ C,
    int M, int N, int K, int relu)
{
    __shared__ __align__(16) unsigned short sA[2][128 * 32];
    __shared__ __align__(16) unsigned short sB[2][64 * 32];
    const int tid  = threadIdx.x;
    const int wave = tid >> 6, lane = tid & 63;
    const int wm = wave >> 1, wn = wave & 1;
    const int quad = lane >> 4, l16 = lane & 15;
    int bm, bn;
    xcd_swizzle(bm, bn);

    const int srow = lane >> 2, scol = (lane & 3) * 8;
    const unsigned short* ga0 = A  + (size_t)(bm * 128 + (wave * 2 + 0) * 16 + srow) * K + scol;
    const unsigned short* ga1 = A  + (size_t)(bm * 128 + (wave * 2 + 1) * 16 + srow) * K + scol;
    const unsigned short* gb0 = BT + (size_t)(bn * 64 + wave * 16 + srow) * K + scol;
    const int oa0 = (wave * 2 + 0) * 512 + lane * 8;
    const int oa1 = (wave * 2 + 1) * 512 + lane * 8;
    const int ob  = wave * 512 + lane * 8;

    v8us aR[2][2], bR[2];
    #pragma unroll
    for (int c = 0; c < 2; ++c) {
        aR[c][0] = *(const v8us*)(ga0 + c * 32);
        aR[c][1] = *(const v8us*)(ga1 + c * 32);
        bR[c]    = *(const v8us*)(gb0 + c * 32);
    }

    v4f acc[4][2];
    #pragma unroll
    for (int i = 0; i < 4; ++i)
        #pragma unroll
        for (int j = 0; j < 2; ++j)
            acc[i][j] = (v4f){0.f, 0.f, 0.f, 0.f};

    for (int kt = 0; kt < K; kt += 64) {
        __syncthreads();
        #pragma unroll
        for (int c = 0; c < 2; ++c) {
            *(v8us*)&sA[c][oa0] = aR[c][0];
            *(v8us*)&sA[c][oa1] = aR[c][1];
            *(v8us*)&sB[c][ob]  = bR[c];
        }
        __syncthreads();
        if (kt + 64 < K) {
            int kn = kt + 64;
            #pragma unroll
            for (int c = 0; c < 2; ++c) {
                aR[c][0] = *(const v8us*)(ga0 + kn + c * 32);
                aR[c][1] = *(const v8us*)(ga1 + kn + c * 32);
                bR[c]    = *(const v8us*)(gb0 + kn + c * 32);
            }
        }

        #pragma unroll
        for (int c = 0; c < 2; ++c) {
            v8bf af[4], bfr[2];
            #pragma unroll
            for (int mt = 0; mt < 4; ++mt)
                af[mt] = *(const v8bf*)&sA[c][(wm * 64 + mt * 16 + l16) * 32 + quad * 8];
            #pragma unroll
            for (int nt = 0; nt < 2; ++nt)
                bfr[nt] = *(const v8bf*)&sB[c][(wn * 32 + nt * 16 + l16) * 32 + quad * 8];
            #pragma unroll
            for (int mt = 0; mt < 4; ++mt)
                #pragma unroll
                for (int nt = 0; nt < 2; ++nt)
                    acc[mt][nt] = __builtin_amdgcn_mfma_f32_16x16x32_bf16(
                        af[mt], bfr[nt], acc[mt][nt], 0, 0, 0);
        }
    }

    #pragma unroll
    for (int mt = 0; mt < 4; ++mt) {
        #pragma unroll
        for (int nt = 0; nt < 2; ++nt) {
            int col = bn * 64 + wn * 32 + nt * 16 + l16;
            float bv = bias ? bias[col] : 0.f;
            #pragma unroll
            for (int r = 0; r < 4; ++r) {
                int row = bm * 128 + wm * 64 + mt * 16 + quad * 4 + r;
                float v = acc[mt][nt][r] + bv;
                if (relu) v = fmaxf(v, 0.f);
                C[(size_t)row * N + col] = f2b(v);
            }
        }
    }
}

// ---------------------------------------------------------------------------
// MFMA flash attention v8 (r14 — known good, 64.5 µs, FETCH 12 MB):
// 32 q/wave + XCD swizzle + pre-scaled Q.
// ---------------------------------------------------------------------------
__global__ __launch_bounds__(256) void attn_mfma(
    const unsigned short* __restrict__ qkv, const unsigned short* __restrict__ VT,
    unsigned short* __restrict__ av)
{
    __shared__ __align__(16) unsigned short sK[64 * 72];
    __shared__ __align__(16) unsigned short sVT[64 * 72];
    __shared__ __align__(16) unsigned short sP[4][32 * 72];
    const int tid  = threadIdx.x;
    const int wave = tid >> 6, lane = tid & 63;
    const int quad = lane >> 4, l16 = lane & 15;
    const int blk = blockIdx.x;
    const int xcd = blk & 7, local = blk >> 3;
    const int bh = xcd * 4 + (local & 3);
    const int qb = local >> 2;
    const int h = bh & 15, b = bh >> 4;
    const int row0 = b * 2048;
    const int qbase = row0 + qb * 128 + wave * 32;
    const size_t qoff = (size_t)h * 192;
    const size_t koff = qoff + 64;

    v8bf qf[2][2];
    #pragma unroll
    for (int qt = 0; qt < 2; ++qt)
        #pragma unroll
        for (int kc = 0; kc < 2; ++kc)
            qf[qt][kc] = *(const v8bf*)&qkv[(size_t)(qbase + qt * 16 + l16) * 3072
                                            + qoff + kc * 32 + quad * 8];

    v4f o[4][2];
    #pragma unroll
    for (int dt = 0; dt < 4; ++dt)
        #pragma unroll
        for (int qt = 0; qt < 2; ++qt)
            o[dt][qt] = (v4f){0.f, 0.f, 0.f, 0.f};
    float ll[2] = {0.f, 0.f};

    const int k_key0 = tid >> 3,        k_oct = (tid & 7) * 8;
    const int k_key1 = (tid + 256) >> 3;
    const int v_d0 = tid >> 3,          v_koct = (tid & 7) * 8;
    const int v_d1 = (tid + 256) >> 3;
    const unsigned short* gK0 = qkv + (size_t)(row0 + k_key0) * 3072 + koff + k_oct;
    const unsigned short* gK1 = qkv + (size_t)(row0 + k_key1) * 3072 + koff + k_oct;
    const unsigned short* gV0 = VT + ((size_t)bh * 64 + v_d0) * 2048 + v_koct;
    const unsigned short* gV1 = VT + ((size_t)bh * 64 + v_d1) * 2048 + v_koct;
    const size_t stepK = (size_t)64 * 3072;
    const size_t stepV = 64;

    v8us kreg0 = *(const v8us*)gK0, kreg1 = *(const v8us*)gK1;
    v8us vreg0 = *(const v8us*)gV0, vreg1 = *(const v8us*)gV1;
    gK0 += stepK; gK1 += stepK; gV0 += stepV; gV1 += stepV;

    for (int kt = 0; kt < 32; ++kt) {
        __syncthreads();
        *(v8us*)&sK[k_key0 * 72 + k_oct] = kreg0;
        *(v8us*)&sK[k_key1 * 72 + k_oct] = kreg1;
        *(v8us*)&sVT[v_d0 * 72 + v_koct] = vreg0;
        *(v8us*)&sVT[v_d1 * 72 + v_koct] = vreg1;
        __syncthreads();
        if (kt < 31) {
            kreg0 = *(const v8us*)gK0; kreg1 = *(const v8us*)gK1;
            vreg0 = *(const v8us*)gV0; vreg1 = *(const v8us*)gV1;
            gK0 += stepK; gK1 += stepK; gV0 += stepV; gV1 += stepV;
        }

        v4f sc[4][2];
        #pragma unroll
        for (int kk = 0; kk < 4; ++kk) {
            #pragma unroll
            for (int qt = 0; qt < 2; ++qt)
                sc[kk][qt] = (v4f){0.f, 0.f, 0.f, 0.f};
            #pragma unroll
            for (int kc = 0; kc < 2; ++kc) {
                v8bf ak = *(const v8bf*)&sK[(kk * 16 + l16) * 72 + kc * 32 + quad * 8];
                #pragma unroll
                for (int qt = 0; qt < 2; ++qt)
                    sc[kk][qt] = __builtin_amdgcn_mfma_f32_16x16x32_bf16(
                        ak, qf[qt][kc], sc[kk][qt], 0, 0, 0);
            }
        }

        #pragma unroll
        for (int qt = 0; qt < 2; ++qt) {
            float ps = 0.f;
            #pragma unroll
            for (int kk = 0; kk < 4; ++kk) {
                v4bf pk;
                #pragma unroll
                for (int rr = 0; rr < 4; ++rr) {
                    float p = __builtin_amdgcn_exp2f(sc[kk][qt][rr]);
                    ps += p;
                    pk[rr] = (__bf16)p;
                }
                *(v4bf*)&sP[wave][(qt * 16 + l16) * 72 + kk * 16 + quad * 4] = pk;
            }
            ll[qt] += ps;
        }

        __asm__ volatile("s_waitcnt lgkmcnt(0)" ::: "memory");

        #pragma unroll
        for (int c = 0; c < 2; ++c) {
            v8bf pb[2];
            #pragma unroll
            for (int qt = 0; qt < 2; ++qt) {
                union { v8bf v; v8us u; } u;
                u.u = *(const v8us*)&sP[wave][(qt * 16 + l16) * 72 + c * 32 + quad * 8];
                pb[qt] = u.v;
            }
            #pragma unroll
            for (int dt = 0; dt < 4; ++dt) {
                v8bf va = *(const v8bf*)&sVT[(dt * 16 + l16) * 72 + c * 32 + quad * 8];
                #pragma unroll
                for (int qt = 0; qt < 2; ++qt)
                    o[dt][qt] = __builtin_amdgcn_mfma_f32_16x16x32_bf16(
                        va, pb[qt], o[dt][qt], 0, 0, 0);
            }
        }
    }

    #pragma unroll
    for (int qt = 0; qt < 2; ++qt) {
        float l = ll[qt];
        l += __shfl_xor(l, 16, 64);
        l += __shfl_xor(l, 32, 64);
        float inv = 1.f / l;
        int qrow = qbase + qt * 16 + l16;
        #pragma unroll
        for (int dt = 0; dt < 4; ++dt) {
            v4bf st;
            #pragma unroll
            for (int rr = 0; rr < 4; ++rr)
                st[rr] = (__bf16)(o[dt][qt][rr] * inv);
            *(v4bf*)&av[(size_t)qrow * 1024 + h * 64 + dt * 16 + quad * 4] = st;
        }
    }
}

// ---------------------------------------------------------------------------
// Fused residual-add + LayerNorm (unchanged — known good)
// ---------------------------------------------------------------------------
template<int RES_F32, int OUT_F32>
__global__ __launch_bounds__(256) void ln_fused(
    const unsigned short* __restrict__ a, const void* __restrict__ residv,
    const float* __restrict__ gamma, const float* __restrict__ beta,
    void* __restrict__ outv)
{
    const int row = blockIdx.x, tid = threadIdx.x;
    const size_t base = (size_t)row * 1024;
    const int c0 = tid * 4;
    ushort4 avv = *(const ushort4*)&a[base + c0];
    float y[4];
    if (RES_F32) {
        float4 rv = *(const float4*)((const float*)residv + base + c0);
        y[0] = b2f(avv.x) + rv.x;
        y[1] = b2f(avv.y) + rv.y;
        y[2] = b2f(avv.z) + rv.z;
        y[3] = b2f(avv.w) + rv.w;
    } else {
        ushort4 rv = *(const ushort4*)((const unsigned short*)residv + base + c0);
        y[0] = b2f(avv.x) + b2f(rv.x);
        y[1] = b2f(avv.y) + b2f(rv.y);
        y[2] = b2f(avv.z) + b2f(rv.z);
        y[3] = b2f(avv.w) + b2f(rv.w);
    }
    float s  = y[0] + y[1] + y[2] + y[3];
    float ss = y[0]*y[0] + y[1]*y[1] + y[2]*y[2] + y[3]*y[3];
    #pragma unroll
    for (int off = 32; off; off >>= 1) {
        s  += __shfl_xor(s, off, 64);
        ss += __shfl_xor(ss, off, 64);
    }
    __shared__ float red[8];
    int wave = tid >> 6, lane = tid & 63;
    if (lane == 0) { red[wave] = s; red[4 + wave] = ss; }
    __syncthreads();
    s  = red[0] + red[1] + red[2] + red[3];
    ss = red[4] + red[5] + red[6] + red[7];
    float mean = s * (1.f / 1024.f);
    float var  = ss * (1.f / 1024.f) - mean * mean;
    float rstd = rsqrtf(var + 1e-5f);
    float4 gv = *(const float4*)&gamma[c0];
    float4 bv = *(const float4*)&beta[c0];
    float r0 = gv.x * (y[0] - mean) * rstd + bv.x;
    float r1 = gv.y * (y[1] - mean) * rstd + bv.y;
    float r2 = gv.z * (y[2] - mean) * rstd + bv.z;
    float r3 = gv.w * (y[3] - mean) * rstd + bv.w;
    if (OUT_F32) {
        float4 ov = {r0, r1, r2, r3};
        *(float4*)((float*)outv + base + c0) = ov;
    } else {
        ushort4 ov;
        ov.x = f2b(r0); ov.y = f2b(r1); ov.z = f2b(r2); ov.w = f2b(r3);
        *(ushort4*)((unsigned short*)outv + base + c0) = ov;
    }
}

// ---------------------------------------------------------------------------
extern "C" void kernel_launch(void* const* d_in, const int* in_sizes, int n_in,
                              void* d_out, int out_size, void* d_ws, size_t ws_size,
                              hipStream_t stream)
{
    (void)in_sizes; (void)n_in; (void)out_size; (void)ws_size;
    const float* x    = (const float*)d_in[0];
    const float* Wqkv = (const float*)d_in[1];
    const float* bqkv = (const float*)d_in[2];
    const float* Wo   = (const float*)d_in[3];
    const float* bo   = (const float*)d_in[4];
    const float* g1   = (const float*)d_in[5];
    const float* be1  = (const float*)d_in[6];
    const float* W1   = (const float*)d_in[7];
    const float* b1   = (const float*)d_in[8];
    const float* W2   = (const float*)d_in[9];
    const float* b2   = (const float*)d_in[10];
    const float* g2   = (const float*)d_in[11];
    const float* be2  = (const float*)d_in[12];
    float* out = (float*)d_out;

    // ws regions (bf16 elems), 28M total. Lifetimes:
    //  R0 (16M): qkv Q/K -> ffn1; tail [12M..16M]: WqkvT
    //  R1 (4M):  VT -> attn_out -> W2T
    //  R2 (4M):  xb -> WoT -> h
    //  R3 (4M):  av -> W1T -> ffn2
    unsigned short* R0 = (unsigned short*)d_ws;
    unsigned short* R1 = R0 + (size_t)16 * 1024 * 1024;
    unsigned short* R2 = R1 + (size_t)4 * 1024 * 1024;
    unsigned short* R3 = R2 + (size_t)4 * 1024 * 1024;
    unsigned short* WqkvT = R0 + (size_t)12 * 1024 * 1024;

    const int M = 4096;
    dim3 blk(256);

    // prep: x -> bf16 (R2); Wqkv^T (into R0 tail)
    convert_f32_bf16<<<dim3(M * 1024 / 1024), blk, 0, stream>>>(x, R2);
    transpose_to_bt<<<dim3(48, 16), blk, 0, stream>>>(Wqkv, WqkvT, 1024, 3072);
    // 1. qkv = xb @ Wqkv + b -> Q(pre-scaled)/K into R0, V transposed into VT (R1)
    gemm_bt<1><<<dim3(24, 32), blk, 0, stream>>>(R2, WqkvT, bqkv, R0, R1, M, 3072, 1024, 0);
    // 2. attention -> av (R3)
    attn_mfma<<<dim3(512), blk, 0, stream>>>(R0, R1, R3);
    // 3. attn_out = av @ Wo + bo -> R1   (VT dead)
    transpose_to_bt<<<dim3(16, 16), blk, 0, stream>>>(Wo, R2, 1024, 1024);
    gemm_bt_n64<<<dim3(16, 32), blk, 0, stream>>>(R3, R2, bo, R1, M, 1024, 1024, 0);
    // 4. h = LN1(attn_out + x) -> R2  (WoT dead)
    ln_fused<1, 0><<<dim3(4096), blk, 0, stream>>>(R1, x, g1, be1, R2);
    // 5. ffn1 = relu(h @ W1 + b1) -> R0  (qkv dead)
    transpose_to_bt<<<dim3(64, 16), blk, 0, stream>>>(W1, R3, 1024, 4096);
    gemm_bt<0><<<dim3(32, 32), blk, 0, stream>>>(R2, R3, b1, R0, nullptr, M, 4096, 1024, 1);
    // 6. ffn2 = ffn1 @ W2 + b2 -> R3  (W1T dead)
    transpose_to_bt<<<dim3(16, 64), blk, 0, stream>>>(W2, R1, 4096, 1024);
    gemm_bt_n64<<<dim3(16, 32), blk, 0, stream>>>(R0, R1, b2, R3, M, 1024, 4096, 0);
    // 7. out = LN2(ffn2 + h)
    ln_fused<0, 1><<<dim3(4096), blk, 0, stream>>>(R3, R2, g2, be2, out);
}